// Round 12
// baseline (169.861 us; speedup 1.0000x reference)
//
#include <hip/hip_runtime.h>
#include <hip/hip_bf16.h>

typedef __attribute__((ext_vector_type(8))) short short8;
typedef __attribute__((ext_vector_type(4))) float f32x4;

#define DEV static __device__ __forceinline__

DEV unsigned short f2bf(float f) {
  union { float f; unsigned u; } v; v.f = f;
  unsigned r = v.u + 0x7FFFu + ((v.u >> 16) & 1u);
  return (unsigned short)(r >> 16);
}
DEV float bf2f(unsigned short b) {
  union { unsigned u; float f; } v; v.u = ((unsigned)b) << 16;
  return v.f;
}

DEV unsigned cvtpk_bf16(float lo, float hi) {
  unsigned r;
  asm("v_cvt_pk_bf16_f32 %0, %1, %2" : "=v"(r) : "v"(lo), "v"(hi));
  return r;
}

DEV void gld_lds16(const void* g, void* l) {
  __builtin_amdgcn_global_load_lds(
      (const __attribute__((address_space(1))) unsigned int*)g,
      (__attribute__((address_space(3))) unsigned int*)l, 16, 0, 0);
}

DEV short8 lds_read8(const unsigned short* base, int byteoff) {
  return *reinterpret_cast<const short8*>(reinterpret_cast<const char*>(base) + byteoff);
}

// ---------------- merged prep: cast x + transpose weights + mask pack ----------------
__global__ __launch_bounds__(256) void prep_kernel(
    const float* __restrict__ x, unsigned short* __restrict__ xb,
    const float* __restrict__ W0, const float* __restrict__ W1,
    const float* __restrict__ W2, const float* __restrict__ W3,
    unsigned short* __restrict__ T0, unsigned short* __restrict__ T1,
    unsigned short* __restrict__ T2, unsigned short* __restrict__ T3,
    const int* __restrict__ mask, unsigned char* __restrict__ mb) {
  __shared__ unsigned short tile[32][33];
  const int bid = blockIdx.x, tid = threadIdx.x;
  if (bid < 4096) {
    int i = bid * 256 + tid;
    float4 v = reinterpret_cast<const float4*>(x)[i];
    ushort4 o;
    o.x = f2bf(v.x); o.y = f2bf(v.y); o.z = f2bf(v.z); o.w = f2bf(v.w);
    reinterpret_cast<ushort4*>(xb)[i] = o;
  } else if (bid < 5120) {
    int r = bid - 4096;
    int z = r >> 8;
    r &= 255;
    const float* W = z == 0 ? W0 : z == 1 ? W1 : z == 2 ? W2 : W3;
    unsigned short* T = z == 0 ? T0 : z == 1 ? T1 : z == 2 ? T2 : T3;
    int tx = tid & 31, ty = tid >> 5;
    int n0 = (r & 15) * 32, k0 = (r >> 4) * 32;
#pragma unroll
    for (int i = 0; i < 32; i += 8)
      tile[ty + i][tx] = f2bf(W[(size_t)(k0 + ty + i) * 512 + n0 + tx]);
    __syncthreads();
#pragma unroll
    for (int i = 0; i < 32; i += 8)
      T[(size_t)(n0 + ty + i) * 512 + k0 + tx] = tile[tx][ty + i];
  } else {
    int i = (bid - 5120) * 256 + tid;
    int4 m4 = reinterpret_cast<const int4*>(mask)[i];
    unsigned v = (m4.x ? 1u : 0u) | ((m4.y ? 1u : 0u) << 8) |
                 ((m4.z ? 1u : 0u) << 16) | ((m4.w ? 1u : 0u) << 24);
    reinterpret_cast<unsigned*>(mb)[i] = v;
  }
}

// ---------------- standalone mask pack (fallback when ws too small; overlays xb) ----------------
__global__ __launch_bounds__(256) void mask_prep_kernel(const int* __restrict__ mask,
                                                        unsigned char* __restrict__ mb) {
  int i = blockIdx.x * 256 + threadIdx.x;
  int4 m4 = reinterpret_cast<const int4*>(mask)[i];
  unsigned v = (m4.x ? 1u : 0u) | ((m4.y ? 1u : 0u) << 8) |
               ((m4.z ? 1u : 0u) << 16) | ((m4.w ? 1u : 0u) << 24);
  reinterpret_cast<unsigned*>(mb)[i] = v;
}

// ---------------- fused QKV projection GEMM (2-phase dbuf pipeline) ----------------
__global__ __launch_bounds__(256) void gemm_proj_kernel(
    const unsigned short* __restrict__ xb,
    const unsigned short* __restrict__ WqT, const unsigned short* __restrict__ WkT,
    const unsigned short* __restrict__ WvT,
    const float* __restrict__ bq, const float* __restrict__ bk, const float* __restrict__ bv,
    unsigned short* __restrict__ qn, unsigned short* __restrict__ kn,
    unsigned short* __restrict__ vn, unsigned short* __restrict__ vT) {
  const int z = blockIdx.z;
  const unsigned short* Wt = z == 0 ? WqT : z == 1 ? WkT : WvT;
  const float* bias = z == 0 ? bq : z == 1 ? bk : bv;
  unsigned short* outp = z == 0 ? qn : z == 1 ? kn : vn;

  __shared__ unsigned short smem[17408];
  unsigned short* As = smem;
  unsigned short* Bs = smem + 8192;

  const int tid = threadIdx.x;
  const int lane = tid & 63;
  const int w = tid >> 6;
  const int wm = w >> 1, wn = w & 1;
  const int lr = lane & 15;
  const int g = lane >> 4;

  const int m0 = blockIdx.x * 128;
  const int n0 = blockIdx.y * 128;

  f32x4 acc[4][4];
#pragma unroll
  for (int i = 0; i < 4; ++i)
#pragma unroll
    for (int j = 0; j < 4; ++j) acc[i][j] = (f32x4){0.f, 0.f, 0.f, 0.f};

#define STAGE_AB(buf, k0)                                                         \
  {                                                                               \
    _Pragma("unroll") for (int p = 0; p < 2; ++p) {                               \
      int slot = tid + 256 * p;                                                   \
      int r = slot >> 2;                                                          \
      int kg = (slot & 3) ^ ((r >> 1) & 3);                                       \
      unsigned short* ldsA = As + (buf)*4096 + (size_t)(w + 4 * p) * 512;         \
      unsigned short* ldsB = Bs + (buf)*4096 + (size_t)(w + 4 * p) * 512;         \
      gld_lds16(xb + (size_t)(m0 + r) * 512 + (k0) + kg * 8, ldsA);               \
      gld_lds16(Wt + (size_t)(n0 + r) * 512 + (k0) + kg * 8, ldsB);               \
    }                                                                             \
  }

  STAGE_AB(0, 0)
  asm volatile("s_waitcnt vmcnt(0)" ::: "memory");
  __builtin_amdgcn_sched_barrier(0);
  __builtin_amdgcn_s_barrier();

  int cur = 0;
  for (int kt = 0; kt < 16; ++kt) {
    if (kt < 15) STAGE_AB(cur ^ 1, (kt + 1) * 32)
    __builtin_amdgcn_sched_barrier(0);

    const unsigned short* Ac = As + cur * 4096;
    const unsigned short* Bc = Bs + cur * 4096;
    short8 af[4], bfr[4];
#pragma unroll
    for (int mi = 0; mi < 4; ++mi) {
      int r = wm * 64 + mi * 16 + lr;
      af[mi] = lds_read8(Ac, (r * 64 + g * 16) ^ (((r >> 1) & 3) << 4));
    }
#pragma unroll
    for (int ni = 0; ni < 4; ++ni) {
      int r = wn * 64 + ni * 16 + lr;
      bfr[ni] = lds_read8(Bc, (r * 64 + g * 16) ^ (((r >> 1) & 3) << 4));
    }
    __builtin_amdgcn_s_setprio(1);
#pragma unroll
    for (int mi = 0; mi < 4; ++mi)
#pragma unroll
      for (int ni = 0; ni < 4; ++ni)
        acc[mi][ni] = __builtin_amdgcn_mfma_f32_16x16x32_bf16(af[mi], bfr[ni], acc[mi][ni], 0, 0, 0);
    __builtin_amdgcn_s_setprio(0);

    asm volatile("s_waitcnt vmcnt(0)" ::: "memory");
    __builtin_amdgcn_sched_barrier(0);
    __builtin_amdgcn_s_barrier();
    __builtin_amdgcn_sched_barrier(0);
    cur ^= 1;
  }

  float biasv[4];
#pragma unroll
  for (int ni = 0; ni < 4; ++ni) biasv[ni] = bias[n0 + wn * 64 + ni * 16 + lr];

#pragma unroll
  for (int mi = 0; mi < 4; ++mi) {
    int rowb = m0 + wm * 64 + mi * 16 + g * 4;
#pragma unroll
    for (int ni = 0; ni < 4; ++ni) {
      int c = n0 + wn * 64 + ni * 16 + lr;
      int h = c >> 6, d = c & 63;
#pragma unroll
      for (int rr = 0; rr < 4; ++rr) {
        float vf = acc[mi][ni][rr] + biasv[ni];
        vf = vf > 0.f ? vf : 0.f;
        unsigned short bvv = f2bf(vf);
        int row = rowb + rr;
        int b = row >> 10, tok = row & 1023;
        outp[((size_t)(b * 8 + h) * 1024 + tok) * 64 + d] = bvv;
        if (z == 2) {
          int cl = wn * 64 + ni * 16 + lr;
          int rl = wm * 64 + mi * 16 + g * 4 + rr;
          smem[cl * 136 + rl] = bvv;
        }
      }
    }
  }
  if (z == 2) {
    __syncthreads();
    int cl = tid >> 1, half = tid & 1;
    int gc = n0 + cl, h = gc >> 6, d = gc & 63;
    int b = m0 >> 10;
    int tokbase = (m0 & 1023) + half * 64;
    size_t base = (size_t)(b * 8 + h) * 65536 + (size_t)d * 1024 + tokbase;
    const unsigned short* src = smem + cl * 136 + half * 64;
#pragma unroll
    for (int j = 0; j < 8; ++j) {
      short8 v8 = *reinterpret_cast<const short8*>(src + j * 8);
      *reinterpret_cast<short8*>(vT + base + j * 8) = v8;
    }
  }
#undef STAGE_AB
}

// ---------------- fused masked-softmax attention (tri-buffer, 2-deep pipeline) ----------------
// 8 waves x 16 q-rows (128 q/block); grid 512 -> exactly 2 blocks/CU.
// Per tile: [mask(t+1)] | [stage(t+2)] | compute(t) | vmcnt(N) | barrier, regions pinned
// by sched_barrier(0) so the per-wave vmem FIFO is deterministic. Steady-state N=14:
// stage(t+1) retired; 4 prev stores + 4 mask + 2 stage + 4 stores may stay in flight.
// LDS 64KB (3x8K K + 3x8K V + 16K P).
__global__ __launch_bounds__(512) void attn_kernel(
    const unsigned short* __restrict__ qg, const unsigned short* __restrict__ kgp,
    const unsigned short* __restrict__ vg, const unsigned short* __restrict__ vTg,
    const unsigned char* __restrict__ mb, float* __restrict__ attw,
    unsigned short* __restrict__ Og) {
  __shared__ unsigned short Ks[3][4096];  // [buf][64 kk][64 d], swizzled by kk&7
  __shared__ unsigned short Vs[3][4096];  // [buf][64 d][64 kk], swizzled by d&7
  __shared__ unsigned short Ps[8192];     // per-wave [16 q][64 kk], swizzled by q&7

  const int tid = threadIdx.x, lane = tid & 63, w = tid >> 6;
  const int lr = lane & 15, g = lane >> 4;

  const int bid = blockIdx.x;
  const int b = bid & 7;          // XCD-pinned batch
  const int idx = bid >> 3;
  const int h = idx >> 3;
  const int qc = idx & 7;
  const int bh = b * 8 + h;

  const int qw = qc * 128 + w * 16;
  const size_t qbase = (size_t)bh * 65536;

  const unsigned short* kbase = kgp + qbase;
  const unsigned short* vbase = vTg + qbase;

  const int srow = w * 8 + (lane >> 3);
  const int ssw = ((lane & 7) ^ (srow & 7)) * 8;

  short8 aq[2];
#pragma unroll
  for (int dc = 0; dc < 2; ++dc)
    aq[dc] = *reinterpret_cast<const short8*>(
        qg + qbase + (size_t)(qw + lr) * 64 + dc * 32 + g * 8);

  f32x4 o[4];
#pragma unroll
  for (int di = 0; di < 4; ++di) o[di] = (f32x4){0.f, 0.f, 0.f, 0.f};
  float lsum = 0.f;

  unsigned short* Pw = Ps + w * 1024;
  const unsigned char* mp = mb + ((size_t)(b * 1024 + qw + lr)) * 1024 + g * 4;
  float* awp = attw + ((size_t)bh * 1024 + qw + lr) * 1024 + g * 4;

#define STAGE_T(kv0, buf)                                                      \
  gld_lds16(kbase + (size_t)((kv0) + srow) * 64 + ssw,                         \
            reinterpret_cast<char*>(Ks[buf]) + w * 1024);                      \
  gld_lds16(vbase + (size_t)srow * 1024 + (kv0) + ssw,                         \
            reinterpret_cast<char*>(Vs[buf]) + w * 1024);

  // prologue: mask(0) (oldest) | stage(0) -> buf0 | stage(1) -> buf1
  unsigned mk[4];
#pragma unroll
  for (int ni = 0; ni < 4; ++ni)
    mk[ni] = *reinterpret_cast<const unsigned*>(mp + ni * 16);
  __builtin_amdgcn_sched_barrier(0);
  STAGE_T(0, 0)
  __builtin_amdgcn_sched_barrier(0);
  STAGE_T(64, 1)
  __builtin_amdgcn_sched_barrier(0);
  // wait mask(0)+stage(0); stage(1)'s 2 ops stay in flight
  asm volatile("s_waitcnt vmcnt(2)" ::: "memory");
  __builtin_amdgcn_sched_barrier(0);
  __builtin_amdgcn_s_barrier();
  __builtin_amdgcn_sched_barrier(0);

#pragma unroll
  for (int t = 0; t < 16; ++t) {
    const int kv0 = t * 64;
    const int cur = t % 3;

    // mask(t+1) loads (oldest ops of this iter)
    unsigned mkn[4];
    if (t < 15) {
#pragma unroll
      for (int ni = 0; ni < 4; ++ni)
        mkn[ni] = *reinterpret_cast<const unsigned*>(mp + kv0 + 64 + ni * 16);
    }
    __builtin_amdgcn_sched_barrier(0);

    // stage(t+2) into buf (t+2)%3 (that buffer was read in iter t-1; barrier passed)
    if (t < 14) {
      STAGE_T(kv0 + 128, (t + 2) % 3)
    }
    __builtin_amdgcn_sched_barrier(0);

    const unsigned short* Kc = Ks[cur];
    const unsigned short* Vc = Vs[cur];

    // S^T = mfma(K, Q)
    f32x4 s[4];
    __builtin_amdgcn_s_setprio(1);
#pragma unroll
    for (int ni = 0; ni < 4; ++ni) {
      int row = ni * 16 + lr;
      s[ni] = (f32x4){0.f, 0.f, 0.f, 0.f};
#pragma unroll
      for (int dc = 0; dc < 2; ++dc) {
        short8 ak = lds_read8(Kc, (row * 128 + dc * 64 + g * 16) ^ ((row & 7) << 4));
        s[ni] = __builtin_amdgcn_mfma_f32_16x16x32_bf16(ak, aq[dc], s[ni], 0, 0, 0);
      }
    }
    __builtin_amdgcn_s_setprio(0);

    // attw stores + mask + exp(sv-16) + P pack
#pragma unroll
    for (int ni = 0; ni < 4; ++ni) {
      f32x4 sv = s[ni] * 0.125f;
      *reinterpret_cast<f32x4*>(awp + kv0 + ni * 16) = sv;
      unsigned m = mk[ni];
      float p0 = (m & 0x000000FFu) ? __expf(sv[0] - 16.f) : 0.f;
      float p1 = (m & 0x0000FF00u) ? __expf(sv[1] - 16.f) : 0.f;
      float p2 = (m & 0x00FF0000u) ? __expf(sv[2] - 16.f) : 0.f;
      float p3 = (m & 0xFF000000u) ? __expf(sv[3] - 16.f) : 0.f;
      lsum += (p0 + p1) + (p2 + p3);
      uint2 pk = make_uint2(cvtpk_bf16(p0, p1), cvtpk_bf16(p2, p3));
      int pbyte = (lr * 128 + ni * 32 + g * 8) ^ ((lr & 7) << 4);
      *reinterpret_cast<uint2*>(reinterpret_cast<char*>(Pw) + pbyte) = pk;
    }

    // O += P @ V
    __builtin_amdgcn_s_setprio(1);
#pragma unroll
    for (int kc = 0; kc < 2; ++kc) {
      short8 ap = lds_read8(Pw, (lr * 128 + kc * 64 + g * 16) ^ ((lr & 7) << 4));
#pragma unroll
      for (int di = 0; di < 4; ++di) {
        int rd = di * 16 + lr;
        short8 bv8 = lds_read8(Vc, (rd * 128 + kc * 64 + g * 16) ^ ((rd & 7) << 4));
        o[di] = __builtin_amdgcn_mfma_f32_16x16x32_bf16(ap, bv8, o[di], 0, 0, 0);
      }
    }
    __builtin_amdgcn_s_setprio(0);
    __builtin_amdgcn_sched_barrier(0);

    // counted drain: guarantee stage(t+1) retired; newer ops stay in flight.
    // FIFO newest-after-stage(t+1): t=0 -> 10; 1<=t<14 -> 14; t=14 -> 12.
    if (t == 0) {
      asm volatile("s_waitcnt vmcnt(10)" ::: "memory");
    } else if (t < 14) {
      asm volatile("s_waitcnt vmcnt(14)" ::: "memory");
    } else if (t == 14) {
      asm volatile("s_waitcnt vmcnt(12)" ::: "memory");
    }
    if (t < 15) {
      __builtin_amdgcn_sched_barrier(0);
      __builtin_amdgcn_s_barrier();
      __builtin_amdgcn_sched_barrier(0);
    }
    if (t < 15) {
#pragma unroll
      for (int ni = 0; ni < 4; ++ni) mk[ni] = mkn[ni];
    }
  }
#undef STAGE_T

  // end-of-kernel row-sum reduce + epilogue (O/l + V residual)
  float l = lsum;
  l += __shfl_xor(l, 16);
  l += __shfl_xor(l, 32);

#pragma unroll
  for (int rr = 0; rr < 4; ++rr) {
    int gq2 = qw + g * 4 + rr;
    float lq = __shfl(l, g * 4 + rr);
    float inv = 1.f / lq;
#pragma unroll
    for (int di = 0; di < 4; ++di) {
      int gd = di * 16 + lr;
      float ov = o[di][rr] * inv + bf2f(vg[qbase + (size_t)gq2 * 64 + gd]);
      Og[((size_t)(b * 1024 + gq2)) * 512 + h * 64 + gd] = f2bf(ov);
    }
  }
}

// ---------------- final GEMM: out = relu(Og @ Wo + bo), fp32 out (2-phase dbuf) ----------------
__global__ __launch_bounds__(256) void gemm_out_kernel(
    const unsigned short* __restrict__ Ab, const unsigned short* __restrict__ WoT,
    const float* __restrict__ bo, float* __restrict__ outp) {
  __shared__ unsigned short smem[16384];
  unsigned short* As = smem;
  unsigned short* Bs = smem + 8192;

  const int tid = threadIdx.x;
  const int lane = tid & 63;
  const int w = tid >> 6;
  const int wm = w >> 1, wn = w & 1;
  const int lr = lane & 15;
  const int g = lane >> 4;
  const int m0 = blockIdx.x * 128;
  const int n0 = blockIdx.y * 128;

  f32x4 acc[4][4];
#pragma unroll
  for (int i = 0; i < 4; ++i)
#pragma unroll
    for (int j = 0; j < 4; ++j) acc[i][j] = (f32x4){0.f, 0.f, 0.f, 0.f};

#define STAGE_AB(buf, k0)                                                         \
  {                                                                               \
    _Pragma("unroll") for (int p = 0; p < 2; ++p) {                               \
      int slot = tid + 256 * p;                                                   \
      int r = slot >> 2;                                                          \
      int kg = (slot & 3) ^ ((r >> 1) & 3);                                       \
      unsigned short* ldsA = As + (buf)*4096 + (size_t)(w + 4 * p) * 512;         \
      unsigned short* ldsB = Bs + (buf)*4096 + (size_t)(w + 4 * p) * 512;         \
      gld_lds16(Ab + (size_t)(m0 + r) * 512 + (k0) + kg * 8, ldsA);               \
      gld_lds16(WoT + (size_t)(n0 + r) * 512 + (k0) + kg * 8, ldsB);              \
    }                                                                             \
  }

  STAGE_AB(0, 0)
  asm volatile("s_waitcnt vmcnt(0)" ::: "memory");
  __builtin_amdgcn_sched_barrier(0);
  __builtin_amdgcn_s_barrier();

  int cur = 0;
  for (int kt = 0; kt < 16; ++kt) {
    if (kt < 15) STAGE_AB(cur ^ 1, (kt + 1) * 32)
    __builtin_amdgcn_sched_barrier(0);

    const unsigned short* Ac = As + cur * 4096;
    const unsigned short* Bc = Bs + cur * 4096;
    short8 af[4], bfr[4];
#pragma unroll
    for (int mi = 0; mi < 4; ++mi) {
      int r = wm * 64 + mi * 16 + lr;
      af[mi] = lds_read8(Ac, (r * 64 + g * 16) ^ (((r >> 1) & 3) << 4));
    }
#pragma unroll
    for (int ni = 0; ni < 4; ++ni) {
      int r = wn * 64 + ni * 16 + lr;
      bfr[ni] = lds_read8(Bc, (r * 64 + g * 16) ^ (((r >> 1) & 3) << 4));
    }
    __builtin_amdgcn_s_setprio(1);
#pragma unroll
    for (int mi = 0; mi < 4; ++mi)
#pragma unroll
      for (int ni = 0; ni < 4; ++ni)
        acc[mi][ni] = __builtin_amdgcn_mfma_f32_16x16x32_bf16(af[mi], bfr[ni], acc[mi][ni], 0, 0, 0);
    __builtin_amdgcn_s_setprio(0);

    asm volatile("s_waitcnt vmcnt(0)" ::: "memory");
    __builtin_amdgcn_sched_barrier(0);
    __builtin_amdgcn_s_barrier();
    __builtin_amdgcn_sched_barrier(0);
    cur ^= 1;
  }
#undef STAGE_AB

  float biasv[4];
#pragma unroll
  for (int ni = 0; ni < 4; ++ni) biasv[ni] = bo[n0 + wn * 64 + ni * 16 + lr];
#pragma unroll
  for (int mi = 0; mi < 4; ++mi) {
    int rowb = m0 + wm * 64 + mi * 16 + g * 4;
#pragma unroll
    for (int ni = 0; ni < 4; ++ni) {
      int c = n0 + wn * 64 + ni * 16 + lr;
#pragma unroll
      for (int rr = 0; rr < 4; ++rr) {
        float vf = acc[mi][ni][rr] + biasv[ni];
        outp[(size_t)(rowb + rr) * 512 + c] = vf > 0.f ? vf : 0.f;
      }
    }
  }
}

extern "C" void kernel_launch(void* const* d_in, const int* in_sizes, int n_in,
                              void* d_out, int out_size, void* d_ws, size_t ws_size,
                              hipStream_t stream) {
  const float* x = (const float*)d_in[0];
  const float* Wv = (const float*)d_in[1];
  const float* bv = (const float*)d_in[2];
  const float* Wk = (const float*)d_in[3];
  const float* bk = (const float*)d_in[4];
  const float* Wq = (const float*)d_in[5];
  const float* bq = (const float*)d_in[6];
  const float* Wo = (const float*)d_in[7];
  const float* bo = (const float*)d_in[8];
  const int* mask = (const int*)d_in[9];

  char* ws = (char*)d_ws;
  unsigned short* xb  = (unsigned short*)(ws);
  unsigned short* WqT = (unsigned short*)(ws + 8388608);
  unsigned short* WkT = (unsigned short*)(ws + 8912896);
  unsigned short* WvT = (unsigned short*)(ws + 9437184);
  unsigned short* WoT = (unsigned short*)(ws + 9961472);
  unsigned short* qn  = (unsigned short*)(ws + 10485760);
  unsigned short* kn  = (unsigned short*)(ws + 18874368);
  unsigned short* vn  = (unsigned short*)(ws + 27262976);
  unsigned short* vT  = (unsigned short*)(ws + 35651584);
  unsigned short* Og  = (unsigned short*)(ws + 44040192);

  const size_t MBB_HI = 52428800;
  const bool big = ws_size >= MBB_HI + 8388608;
  unsigned char* mbb = big ? (unsigned char*)(ws + MBB_HI) : (unsigned char*)ws;

  float* outp = (float*)d_out;
  float* attw = (float*)d_out + 4194304;

  prep_kernel<<<big ? 13312 : 5120, 256, 0, stream>>>(
      x, xb, Wq, Wk, Wv, Wo, WqT, WkT, WvT, WoT, mask, mbb);

  dim3 gp(64, 4, 3);
  gemm_proj_kernel<<<gp, 256, 0, stream>>>(xb, WqT, WkT, WvT, bq, bk, bv, qn, kn, vn, vT);

  if (!big) mask_prep_kernel<<<8192, 256, 0, stream>>>(mask, mbb);

  attn_kernel<<<512, 512, 0, stream>>>(qn, kn, vn, vT, mbb, attw, Og);

  dim3 go(64, 4);
  gemm_out_kernel<<<go, 256, 0, stream>>>(Og, WoT, bo, outp);
}

// Round 13
// 132.364 us; speedup vs baseline: 1.2833x; 1.2833x over previous
//
#include <hip/hip_runtime.h>
#include <hip/hip_bf16.h>

typedef __attribute__((ext_vector_type(8))) short short8;
typedef __attribute__((ext_vector_type(4))) float f32x4;

#define DEV static __device__ __forceinline__

DEV unsigned short f2bf(float f) {
  union { float f; unsigned u; } v; v.f = f;
  unsigned r = v.u + 0x7FFFu + ((v.u >> 16) & 1u);
  return (unsigned short)(r >> 16);
}
DEV float bf2f(unsigned short b) {
  union { unsigned u; float f; } v; v.u = ((unsigned)b) << 16;
  return v.f;
}

DEV unsigned cvtpk_bf16(float lo, float hi) {
  unsigned r;
  asm("v_cvt_pk_bf16_f32 %0, %1, %2" : "=v"(r) : "v"(lo), "v"(hi));
  return r;
}

DEV void gld_lds16(const void* g, void* l) {
  __builtin_amdgcn_global_load_lds(
      (const __attribute__((address_space(1))) unsigned int*)g,
      (__attribute__((address_space(3))) unsigned int*)l, 16, 0, 0);
}

DEV short8 lds_read8(const unsigned short* base, int byteoff) {
  return *reinterpret_cast<const short8*>(reinterpret_cast<const char*>(base) + byteoff);
}

// ---------------- merged prep: cast x + transpose weights + mask pack ----------------
__global__ __launch_bounds__(256) void prep_kernel(
    const float* __restrict__ x, unsigned short* __restrict__ xb,
    const float* __restrict__ W0, const float* __restrict__ W1,
    const float* __restrict__ W2, const float* __restrict__ W3,
    unsigned short* __restrict__ T0, unsigned short* __restrict__ T1,
    unsigned short* __restrict__ T2, unsigned short* __restrict__ T3,
    const int* __restrict__ mask, unsigned char* __restrict__ mb) {
  __shared__ unsigned short tile[32][33];
  const int bid = blockIdx.x, tid = threadIdx.x;
  if (bid < 4096) {
    int i = bid * 256 + tid;
    float4 v = reinterpret_cast<const float4*>(x)[i];
    ushort4 o;
    o.x = f2bf(v.x); o.y = f2bf(v.y); o.z = f2bf(v.z); o.w = f2bf(v.w);
    reinterpret_cast<ushort4*>(xb)[i] = o;
  } else if (bid < 5120) {
    int r = bid - 4096;
    int z = r >> 8;
    r &= 255;
    const float* W = z == 0 ? W0 : z == 1 ? W1 : z == 2 ? W2 : W3;
    unsigned short* T = z == 0 ? T0 : z == 1 ? T1 : z == 2 ? T2 : T3;
    int tx = tid & 31, ty = tid >> 5;
    int n0 = (r & 15) * 32, k0 = (r >> 4) * 32;
#pragma unroll
    for (int i = 0; i < 32; i += 8)
      tile[ty + i][tx] = f2bf(W[(size_t)(k0 + ty + i) * 512 + n0 + tx]);
    __syncthreads();
#pragma unroll
    for (int i = 0; i < 32; i += 8)
      T[(size_t)(n0 + ty + i) * 512 + k0 + tx] = tile[tx][ty + i];
  } else {
    int i = (bid - 5120) * 256 + tid;
    int4 m4 = reinterpret_cast<const int4*>(mask)[i];
    unsigned v = (m4.x ? 1u : 0u) | ((m4.y ? 1u : 0u) << 8) |
                 ((m4.z ? 1u : 0u) << 16) | ((m4.w ? 1u : 0u) << 24);
    reinterpret_cast<unsigned*>(mb)[i] = v;
  }
}

// ---------------- standalone mask pack (fallback when ws too small; overlays xb) ----------------
__global__ __launch_bounds__(256) void mask_prep_kernel(const int* __restrict__ mask,
                                                        unsigned char* __restrict__ mb) {
  int i = blockIdx.x * 256 + threadIdx.x;
  int4 m4 = reinterpret_cast<const int4*>(mask)[i];
  unsigned v = (m4.x ? 1u : 0u) | ((m4.y ? 1u : 0u) << 8) |
               ((m4.z ? 1u : 0u) << 16) | ((m4.w ? 1u : 0u) << 24);
  reinterpret_cast<unsigned*>(mb)[i] = v;
}

// ---------------- fused QKV projection GEMM (2-phase dbuf pipeline) ----------------
__global__ __launch_bounds__(256) void gemm_proj_kernel(
    const unsigned short* __restrict__ xb,
    const unsigned short* __restrict__ WqT, const unsigned short* __restrict__ WkT,
    const unsigned short* __restrict__ WvT,
    const float* __restrict__ bq, const float* __restrict__ bk, const float* __restrict__ bv,
    unsigned short* __restrict__ qn, unsigned short* __restrict__ kn,
    unsigned short* __restrict__ vn, unsigned short* __restrict__ vT) {
  const int z = blockIdx.z;
  const unsigned short* Wt = z == 0 ? WqT : z == 1 ? WkT : WvT;
  const float* bias = z == 0 ? bq : z == 1 ? bk : bv;
  unsigned short* outp = z == 0 ? qn : z == 1 ? kn : vn;

  __shared__ unsigned short smem[17408];
  unsigned short* As = smem;
  unsigned short* Bs = smem + 8192;

  const int tid = threadIdx.x;
  const int lane = tid & 63;
  const int w = tid >> 6;
  const int wm = w >> 1, wn = w & 1;
  const int lr = lane & 15;
  const int g = lane >> 4;

  const int m0 = blockIdx.x * 128;
  const int n0 = blockIdx.y * 128;

  f32x4 acc[4][4];
#pragma unroll
  for (int i = 0; i < 4; ++i)
#pragma unroll
    for (int j = 0; j < 4; ++j) acc[i][j] = (f32x4){0.f, 0.f, 0.f, 0.f};

#define STAGE_AB(buf, k0)                                                         \
  {                                                                               \
    _Pragma("unroll") for (int p = 0; p < 2; ++p) {                               \
      int slot = tid + 256 * p;                                                   \
      int r = slot >> 2;                                                          \
      int kg = (slot & 3) ^ ((r >> 1) & 3);                                       \
      unsigned short* ldsA = As + (buf)*4096 + (size_t)(w + 4 * p) * 512;         \
      unsigned short* ldsB = Bs + (buf)*4096 + (size_t)(w + 4 * p) * 512;         \
      gld_lds16(xb + (size_t)(m0 + r) * 512 + (k0) + kg * 8, ldsA);               \
      gld_lds16(Wt + (size_t)(n0 + r) * 512 + (k0) + kg * 8, ldsB);               \
    }                                                                             \
  }

  STAGE_AB(0, 0)
  asm volatile("s_waitcnt vmcnt(0)" ::: "memory");
  __builtin_amdgcn_sched_barrier(0);
  __builtin_amdgcn_s_barrier();

  int cur = 0;
  for (int kt = 0; kt < 16; ++kt) {
    if (kt < 15) STAGE_AB(cur ^ 1, (kt + 1) * 32)
    __builtin_amdgcn_sched_barrier(0);

    const unsigned short* Ac = As + cur * 4096;
    const unsigned short* Bc = Bs + cur * 4096;
    short8 af[4], bfr[4];
#pragma unroll
    for (int mi = 0; mi < 4; ++mi) {
      int r = wm * 64 + mi * 16 + lr;
      af[mi] = lds_read8(Ac, (r * 64 + g * 16) ^ (((r >> 1) & 3) << 4));
    }
#pragma unroll
    for (int ni = 0; ni < 4; ++ni) {
      int r = wn * 64 + ni * 16 + lr;
      bfr[ni] = lds_read8(Bc, (r * 64 + g * 16) ^ (((r >> 1) & 3) << 4));
    }
    __builtin_amdgcn_s_setprio(1);
#pragma unroll
    for (int mi = 0; mi < 4; ++mi)
#pragma unroll
      for (int ni = 0; ni < 4; ++ni)
        acc[mi][ni] = __builtin_amdgcn_mfma_f32_16x16x32_bf16(af[mi], bfr[ni], acc[mi][ni], 0, 0, 0);
    __builtin_amdgcn_s_setprio(0);

    asm volatile("s_waitcnt vmcnt(0)" ::: "memory");
    __builtin_amdgcn_sched_barrier(0);
    __builtin_amdgcn_s_barrier();
    __builtin_amdgcn_sched_barrier(0);
    cur ^= 1;
  }

  float biasv[4];
#pragma unroll
  for (int ni = 0; ni < 4; ++ni) biasv[ni] = bias[n0 + wn * 64 + ni * 16 + lr];

#pragma unroll
  for (int mi = 0; mi < 4; ++mi) {
    int rowb = m0 + wm * 64 + mi * 16 + g * 4;
#pragma unroll
    for (int ni = 0; ni < 4; ++ni) {
      int c = n0 + wn * 64 + ni * 16 + lr;
      int h = c >> 6, d = c & 63;
#pragma unroll
      for (int rr = 0; rr < 4; ++rr) {
        float vf = acc[mi][ni][rr] + biasv[ni];
        vf = vf > 0.f ? vf : 0.f;
        unsigned short bvv = f2bf(vf);
        int row = rowb + rr;
        int b = row >> 10, tok = row & 1023;
        outp[((size_t)(b * 8 + h) * 1024 + tok) * 64 + d] = bvv;
        if (z == 2) {
          int cl = wn * 64 + ni * 16 + lr;
          int rl = wm * 64 + mi * 16 + g * 4 + rr;
          smem[cl * 136 + rl] = bvv;
        }
      }
    }
  }
  if (z == 2) {
    __syncthreads();
    int cl = tid >> 1, half = tid & 1;
    int gc = n0 + cl, h = gc >> 6, d = gc & 63;
    int b = m0 >> 10;
    int tokbase = (m0 & 1023) + half * 64;
    size_t base = (size_t)(b * 8 + h) * 65536 + (size_t)d * 1024 + tokbase;
    const unsigned short* src = smem + cl * 136 + half * 64;
#pragma unroll
    for (int j = 0; j < 8; ++j) {
      short8 v8 = *reinterpret_cast<const short8*>(src + j * 8);
      *reinterpret_cast<short8*>(vT + base + j * 8) = v8;
    }
  }
#undef STAGE_AB
}

// ---------------- fused masked-softmax attention (R10/R11 best config) ----------------
// 8 waves x 16 q-rows (128 q/block); grid 512 -> exactly 2 blocks/CU resident.
// Shared dbuf K/V staging, counted vmcnt(4) drain, XCD remap b = bid&7. LDS 48KB.
__global__ __launch_bounds__(512) void attn_kernel(
    const unsigned short* __restrict__ qg, const unsigned short* __restrict__ kgp,
    const unsigned short* __restrict__ vg, const unsigned short* __restrict__ vTg,
    const unsigned char* __restrict__ mb, float* __restrict__ attw,
    unsigned short* __restrict__ Og) {
  __shared__ unsigned short Ks[2][4096];  // [buf][64 kk][64 d], swizzled by kk&7
  __shared__ unsigned short Vs[2][4096];  // [buf][64 d][64 kk], swizzled by d&7
  __shared__ unsigned short Ps[8192];     // per-wave [16 q][64 kk], swizzled by q&7

  const int tid = threadIdx.x, lane = tid & 63, w = tid >> 6;
  const int lr = lane & 15, g = lane >> 4;

  const int bid = blockIdx.x;
  const int b = bid & 7;          // XCD-pinned batch
  const int idx = bid >> 3;
  const int h = idx >> 3;
  const int qc = idx & 7;
  const int bh = b * 8 + h;

  const int qw = qc * 128 + w * 16;
  const size_t qbase = (size_t)bh * 65536;

  const unsigned short* kbase = kgp + qbase;
  const unsigned short* vbase = vTg + qbase;

  const int srow = w * 8 + (lane >> 3);
  const int ssw = ((lane & 7) ^ (srow & 7)) * 8;

  short8 aq[2];
#pragma unroll
  for (int dc = 0; dc < 2; ++dc)
    aq[dc] = *reinterpret_cast<const short8*>(
        qg + qbase + (size_t)(qw + lr) * 64 + dc * 32 + g * 8);

  f32x4 o[4];
#pragma unroll
  for (int di = 0; di < 4; ++di) o[di] = (f32x4){0.f, 0.f, 0.f, 0.f};
  float lsum = 0.f;

  unsigned short* Pw = Ps + w * 1024;
  const unsigned char* mp = mb + ((size_t)(b * 1024 + qw + lr)) * 1024 + g * 4;
  float* awp = attw + ((size_t)bh * 1024 + qw + lr) * 1024 + g * 4;

  gld_lds16(kbase + (size_t)srow * 64 + ssw, reinterpret_cast<char*>(Ks[0]) + w * 1024);
  gld_lds16(vbase + (size_t)srow * 1024 + ssw, reinterpret_cast<char*>(Vs[0]) + w * 1024);
  asm volatile("s_waitcnt vmcnt(0)" ::: "memory");
  __builtin_amdgcn_sched_barrier(0);
  __builtin_amdgcn_s_barrier();

  int cur = 0;
  for (int t = 0; t < 16; ++t) {
    const int kv0 = t * 64;

    unsigned mk[4];
#pragma unroll
    for (int ni = 0; ni < 4; ++ni)
      mk[ni] = *reinterpret_cast<const unsigned*>(mp + kv0 + ni * 16);
    __builtin_amdgcn_sched_barrier(0);

    if (t < 15) {
      const int kn0 = kv0 + 64;
      gld_lds16(kbase + (size_t)(kn0 + srow) * 64 + ssw,
                reinterpret_cast<char*>(Ks[cur ^ 1]) + w * 1024);
      gld_lds16(vbase + (size_t)srow * 1024 + kn0 + ssw,
                reinterpret_cast<char*>(Vs[cur ^ 1]) + w * 1024);
    }
    __builtin_amdgcn_sched_barrier(0);

    const unsigned short* Kc = Ks[cur];
    const unsigned short* Vc = Vs[cur];

    f32x4 s[4];
    __builtin_amdgcn_s_setprio(1);
#pragma unroll
    for (int ni = 0; ni < 4; ++ni) {
      int row = ni * 16 + lr;
      s[ni] = (f32x4){0.f, 0.f, 0.f, 0.f};
#pragma unroll
      for (int dc = 0; dc < 2; ++dc) {
        short8 ak = lds_read8(Kc, (row * 128 + dc * 64 + g * 16) ^ ((row & 7) << 4));
        s[ni] = __builtin_amdgcn_mfma_f32_16x16x32_bf16(ak, aq[dc], s[ni], 0, 0, 0);
      }
    }
    __builtin_amdgcn_s_setprio(0);

#pragma unroll
    for (int ni = 0; ni < 4; ++ni) {
      f32x4 sv = s[ni] * 0.125f;
      *reinterpret_cast<f32x4*>(awp + kv0 + ni * 16) = sv;
      unsigned m = mk[ni];
      float p0 = (m & 0x000000FFu) ? __expf(sv[0] - 16.f) : 0.f;
      float p1 = (m & 0x0000FF00u) ? __expf(sv[1] - 16.f) : 0.f;
      float p2 = (m & 0x00FF0000u) ? __expf(sv[2] - 16.f) : 0.f;
      float p3 = (m & 0xFF000000u) ? __expf(sv[3] - 16.f) : 0.f;
      lsum += (p0 + p1) + (p2 + p3);
      uint2 pk = make_uint2(cvtpk_bf16(p0, p1), cvtpk_bf16(p2, p3));
      int pbyte = (lr * 128 + ni * 32 + g * 8) ^ ((lr & 7) << 4);
      *reinterpret_cast<uint2*>(reinterpret_cast<char*>(Pw) + pbyte) = pk;
    }

    __builtin_amdgcn_s_setprio(1);
#pragma unroll
    for (int kc = 0; kc < 2; ++kc) {
      short8 ap = lds_read8(Pw, (lr * 128 + kc * 64 + g * 16) ^ ((lr & 7) << 4));
#pragma unroll
      for (int di = 0; di < 4; ++di) {
        int rd = di * 16 + lr;
        short8 bv8 = lds_read8(Vc, (rd * 128 + kc * 64 + g * 16) ^ ((rd & 7) << 4));
        o[di] = __builtin_amdgcn_mfma_f32_16x16x32_bf16(ap, bv8, o[di], 0, 0, 0);
      }
    }
    __builtin_amdgcn_s_setprio(0);

    asm volatile("s_waitcnt vmcnt(4)" ::: "memory");
    __builtin_amdgcn_sched_barrier(0);
    __builtin_amdgcn_s_barrier();
    __builtin_amdgcn_sched_barrier(0);
    cur ^= 1;
  }

  float l = lsum;
  l += __shfl_xor(l, 16);
  l += __shfl_xor(l, 32);

#pragma unroll
  for (int rr = 0; rr < 4; ++rr) {
    int gq2 = qw + g * 4 + rr;
    float lq = __shfl(l, g * 4 + rr);
    float inv = 1.f / lq;
#pragma unroll
    for (int di = 0; di < 4; ++di) {
      int gd = di * 16 + lr;
      float ov = o[di][rr] * inv + bf2f(vg[qbase + (size_t)gq2 * 64 + gd]);
      Og[((size_t)(b * 1024 + gq2)) * 512 + h * 64 + gd] = f2bf(ov);
    }
  }
}

// ---------------- final GEMM: out = relu(Og @ Wo + bo), fp32 out (2-phase dbuf) ----------------
__global__ __launch_bounds__(256) void gemm_out_kernel(
    const unsigned short* __restrict__ Ab, const unsigned short* __restrict__ WoT,
    const float* __restrict__ bo, float* __restrict__ outp) {
  __shared__ unsigned short smem[16384];
  unsigned short* As = smem;
  unsigned short* Bs = smem + 8192;

  const int tid = threadIdx.x;
  const int lane = tid & 63;
  const int w = tid >> 6;
  const int wm = w >> 1, wn = w & 1;
  const int lr = lane & 15;
  const int g = lane >> 4;
  const int m0 = blockIdx.x * 128;
  const int n0 = blockIdx.y * 128;

  f32x4 acc[4][4];
#pragma unroll
  for (int i = 0; i < 4; ++i)
#pragma unroll
    for (int j = 0; j < 4; ++j) acc[i][j] = (f32x4){0.f, 0.f, 0.f, 0.f};

#define STAGE_AB(buf, k0)                                                         \
  {                                                                               \
    _Pragma("unroll") for (int p = 0; p < 2; ++p) {                               \
      int slot = tid + 256 * p;                                                   \
      int r = slot >> 2;                                                          \
      int kg = (slot & 3) ^ ((r >> 1) & 3);                                       \
      unsigned short* ldsA = As + (buf)*4096 + (size_t)(w + 4 * p) * 512;         \
      unsigned short* ldsB = Bs + (buf)*4096 + (size_t)(w + 4 * p) * 512;         \
      gld_lds16(Ab + (size_t)(m0 + r) * 512 + (k0) + kg * 8, ldsA);               \
      gld_lds16(WoT + (size_t)(n0 + r) * 512 + (k0) + kg * 8, ldsB);              \
    }                                                                             \
  }

  STAGE_AB(0, 0)
  asm volatile("s_waitcnt vmcnt(0)" ::: "memory");
  __builtin_amdgcn_sched_barrier(0);
  __builtin_amdgcn_s_barrier();

  int cur = 0;
  for (int kt = 0; kt < 16; ++kt) {
    if (kt < 15) STAGE_AB(cur ^ 1, (kt + 1) * 32)
    __builtin_amdgcn_sched_barrier(0);

    const unsigned short* Ac = As + cur * 4096;
    const unsigned short* Bc = Bs + cur * 4096;
    short8 af[4], bfr[4];
#pragma unroll
    for (int mi = 0; mi < 4; ++mi) {
      int r = wm * 64 + mi * 16 + lr;
      af[mi] = lds_read8(Ac, (r * 64 + g * 16) ^ (((r >> 1) & 3) << 4));
    }
#pragma unroll
    for (int ni = 0; ni < 4; ++ni) {
      int r = wn * 64 + ni * 16 + lr;
      bfr[ni] = lds_read8(Bc, (r * 64 + g * 16) ^ (((r >> 1) & 3) << 4));
    }
    __builtin_amdgcn_s_setprio(1);
#pragma unroll
    for (int mi = 0; mi < 4; ++mi)
#pragma unroll
      for (int ni = 0; ni < 4; ++ni)
        acc[mi][ni] = __builtin_amdgcn_mfma_f32_16x16x32_bf16(af[mi], bfr[ni], acc[mi][ni], 0, 0, 0);
    __builtin_amdgcn_s_setprio(0);

    asm volatile("s_waitcnt vmcnt(0)" ::: "memory");
    __builtin_amdgcn_sched_barrier(0);
    __builtin_amdgcn_s_barrier();
    __builtin_amdgcn_sched_barrier(0);
    cur ^= 1;
  }
#undef STAGE_AB

  float biasv[4];
#pragma unroll
  for (int ni = 0; ni < 4; ++ni) biasv[ni] = bo[n0 + wn * 64 + ni * 16 + lr];
#pragma unroll
  for (int mi = 0; mi < 4; ++mi) {
    int rowb = m0 + wm * 64 + mi * 16 + g * 4;
#pragma unroll
    for (int ni = 0; ni < 4; ++ni) {
      int c = n0 + wn * 64 + ni * 16 + lr;
#pragma unroll
      for (int rr = 0; rr < 4; ++rr) {
        float vf = acc[mi][ni][rr] + biasv[ni];
        outp[(size_t)(rowb + rr) * 512 + c] = vf > 0.f ? vf : 0.f;
      }
    }
  }
}

extern "C" void kernel_launch(void* const* d_in, const int* in_sizes, int n_in,
                              void* d_out, int out_size, void* d_ws, size_t ws_size,
                              hipStream_t stream) {
  const float* x = (const float*)d_in[0];
  const float* Wv = (const float*)d_in[1];
  const float* bv = (const float*)d_in[2];
  const float* Wk = (const float*)d_in[3];
  const float* bk = (const float*)d_in[4];
  const float* Wq = (const float*)d_in[5];
  const float* bq = (const float*)d_in[6];
  const float* Wo = (const float*)d_in[7];
  const float* bo = (const float*)d_in[8];
  const int* mask = (const int*)d_in[9];

  char* ws = (char*)d_ws;
  unsigned short* xb  = (unsigned short*)(ws);
  unsigned short* WqT = (unsigned short*)(ws + 8388608);
  unsigned short* WkT = (unsigned short*)(ws + 8912896);
  unsigned short* WvT = (unsigned short*)(ws + 9437184);
  unsigned short* WoT = (unsigned short*)(ws + 9961472);
  unsigned short* qn  = (unsigned short*)(ws + 10485760);
  unsigned short* kn  = (unsigned short*)(ws + 18874368);
  unsigned short* vn  = (unsigned short*)(ws + 27262976);
  unsigned short* vT  = (unsigned short*)(ws + 35651584);
  unsigned short* Og  = (unsigned short*)(ws + 44040192);

  const size_t MBB_HI = 52428800;
  const bool big = ws_size >= MBB_HI + 8388608;
  unsigned char* mbb = big ? (unsigned char*)(ws + MBB_HI) : (unsigned char*)ws;

  float* outp = (float*)d_out;
  float* attw = (float*)d_out + 4194304;

  prep_kernel<<<big ? 13312 : 5120, 256, 0, stream>>>(
      x, xb, Wq, Wk, Wv, Wo, WqT, WkT, WvT, WoT, mask, mbb);

  dim3 gp(64, 4, 3);
  gemm_proj_kernel<<<gp, 256, 0, stream>>>(xb, WqT, WkT, WvT, bq, bk, bv, qn, kn, vn, vT);

  if (!big) mask_prep_kernel<<<8192, 256, 0, stream>>>(mask, mbb);

  attn_kernel<<<512, 512, 0, stream>>>(qn, kn, vn, vT, mbb, attw, Og);

  dim3 go(64, 4);
  gemm_out_kernel<<<go, 256, 0, stream>>>(Og, WoT, bo, outp);
}